// Round 2
// baseline (3596.376 us; speedup 1.0000x reference)
//
#include <hip/hip_runtime.h>
#include <hip/hip_bf16.h>
#include <math.h>

#define NNODES 100000
#define EDIM 128

typedef __bf16 bf16x8 __attribute__((ext_vector_type(8)));
typedef __bf16 bf16x4 __attribute__((ext_vector_type(4)));
typedef float f32x4 __attribute__((ext_vector_type(4)));

// mish(x) = x*tanh(softplus(x)) = x*(u^2+2u)/(u^2+2u+2), u=e^x (clamp: tanh saturated for x>15)
__device__ __forceinline__ float mishf(float x) {
  float u = __expf(fminf(x, 15.f));
  float num = u * (u + 2.f);
  return x * num * __builtin_amdgcn_rcpf(num + 2.f);
}

// exp(12*y) as double via fp32 exp2 on fractional part + exponent bit-pack
__device__ __forceinline__ double exp12(float y) {
  float t = y * 17.312340490667562f;  // 12*log2(e)
  t = fminf(fmaxf(t, -20000.f), 20000.f);
  float ti = floorf(t);
  float m = exp2f(t - ti);
  int ei = (int)ti;
  ei = ei < -1000 ? -1000 : (ei > 1000 ? 1000 : ei);
  double sc = __longlong_as_double(((long long)(1023 + ei)) << 52);
  return (double)m * sc;
}

// log(S)/12 via fp64 bit extraction; S<=0 (empty segment) -> log(1e-16)/12
__device__ __forceinline__ float logS12(double S) {
  if (!(S > 0.0)) return -3.0701134f;
  long long b = __double_as_longlong(S);
  int e2 = (int)((b >> 52) & 0x7FF) - 1023;
  float mf = __uint_as_float(0x3F800000u | (unsigned)((b >> 29) & 0x7FFFFF));
  return ((float)e2 + log2f(mf)) * 0.05776226504666211f;  // ln2/12
}

__global__ void k_sentinel(float* out, int n) {
  int i = blockIdx.x * 256 + threadIdx.x;
  if (i < n) out[i] = 1.0e6f;
}

struct TransDesc {
  const float* src[8];
  __bf16* dst[8];
  int R[8];
  int C[8];
  int tstart[9];
};

// dst[c*R + r] = (bf16)src[r*C + c]  (W[k][n] fp32 -> Wt[n][k] bf16), 8 matrices
__global__ void k_transpose_all(TransDesc td) {
  __shared__ float tile[32][33];
  int b = blockIdx.x;
  int m = 0;
  while (m < 7 && b >= td.tstart[m + 1]) m++;
  int t = b - td.tstart[m];
  int R = td.R[m], C = td.C[m];
  int tcols = C >> 5;
  int by = t / tcols, bx = t - by * tcols;
  int tx = threadIdx.x & 31, ty = threadIdx.x >> 5;
  const float* src = td.src[m];
  __bf16* dst = td.dst[m];
  for (int i = 0; i < 32; i += 8)
    tile[ty + i][tx] = src[(size_t)(by * 32 + ty + i) * C + bx * 32 + tx];
  __syncthreads();
  for (int i = 0; i < 32; i += 8)
    dst[(size_t)(bx * 32 + ty + i) * R + by * 32 + tx] = (__bf16)tile[tx][ty + i];
}

// arity-2 relation: x=[h[av[2a]],h[av[2a+1]]] (K=256), y = x + mish(x@W1+b1)@W2+b2,
// epilogue: seg[node][feat] += exp(12*y)  (fp64 atomic). Residual x from global fp32.
__global__ __launch_bounds__(256, 2) void k_rel2(
    const float* __restrict__ h, const int* __restrict__ av,
    const __bf16* __restrict__ wt1, const float* __restrict__ b1,
    const __bf16* __restrict__ wt2, const float* __restrict__ b2,
    double* __restrict__ seg, int A) {
  __shared__ __align__(16) __bf16 xs[64][264];
  __shared__ int avs[128];
  const int tid = threadIdx.x;
  const int lane = tid & 63;
  const int w = tid >> 6;
  const int row0 = blockIdx.x * 64;

  if (tid < 128) {
    int i2 = row0 * 2 + tid;
    avs[tid] = (i2 < 2 * A) ? av[i2] : 0;
  }
  // gather stage: 64 rows x 256 fp32 -> bf16 LDS
  for (int i = 0; i < 16; ++i) {
    int s = tid + i * 256;      // [0,4096)
    int r = s >> 6, o = s & 63; // o: 16B fp32 chunk (4 floats)
    int a = row0 + r;
    float4 f = {0.f, 0.f, 0.f, 0.f};
    if (a < A) {
      int node = av[2 * a + (o >> 5)];
      f = *(const float4*)(h + (size_t)node * 128 + (o & 31) * 4);
    }
    bf16x4 p = {(__bf16)f.x, (__bf16)f.y, (__bf16)f.z, (__bf16)f.w};
    *(bf16x4*)&xs[r][o * 4] = p;
  }
  __syncthreads();

  const int lhi = lane >> 4, llo = lane & 15;
  const int cb = w * 64;

  f32x4 acc1[4][4];
#pragma unroll
  for (int rt = 0; rt < 4; rt++)
#pragma unroll
    for (int ct = 0; ct < 4; ct++) acc1[rt][ct] = (f32x4){0.f, 0.f, 0.f, 0.f};

#pragma unroll
  for (int kk = 0; kk < 8; ++kk) {
    int k = kk * 32 + lhi * 8;
    bf16x8 af[4], bfr[4];
#pragma unroll
    for (int rt = 0; rt < 4; rt++) af[rt] = *(const bf16x8*)&xs[rt * 16 + llo][k];
#pragma unroll
    for (int ct = 0; ct < 4; ct++)
      bfr[ct] = *(const bf16x8*)(wt1 + (size_t)(cb + ct * 16 + llo) * 256 + k);
#pragma unroll
    for (int rt = 0; rt < 4; rt++)
#pragma unroll
      for (int ct = 0; ct < 4; ct++)
        acc1[rt][ct] = __builtin_amdgcn_mfma_f32_16x16x32_bf16(af[rt], bfr[ct], acc1[rt][ct], 0, 0, 0);
  }
  __syncthreads();

  float b1v[4];
#pragma unroll
  for (int ct = 0; ct < 4; ct++) b1v[ct] = b1[cb + ct * 16 + llo];
#pragma unroll
  for (int rt = 0; rt < 4; rt++)
#pragma unroll
    for (int ct = 0; ct < 4; ct++)
#pragma unroll
      for (int i = 0; i < 4; i++)
        xs[rt * 16 + lhi * 4 + i][cb + ct * 16 + llo] = (__bf16)mishf(acc1[rt][ct][i] + b1v[ct]);
  __syncthreads();

  f32x4 acc2[4][4];
#pragma unroll
  for (int rt = 0; rt < 4; rt++)
#pragma unroll
    for (int ct = 0; ct < 4; ct++) acc2[rt][ct] = (f32x4){0.f, 0.f, 0.f, 0.f};

#pragma unroll
  for (int kk = 0; kk < 8; ++kk) {
    int k = kk * 32 + lhi * 8;
    bf16x8 af[4], bfr[4];
#pragma unroll
    for (int rt = 0; rt < 4; rt++) af[rt] = *(const bf16x8*)&xs[rt * 16 + llo][k];
#pragma unroll
    for (int ct = 0; ct < 4; ct++)
      bfr[ct] = *(const bf16x8*)(wt2 + (size_t)(cb + ct * 16 + llo) * 256 + k);
#pragma unroll
    for (int rt = 0; rt < 4; rt++)
#pragma unroll
      for (int ct = 0; ct < 4; ct++)
        acc2[rt][ct] = __builtin_amdgcn_mfma_f32_16x16x32_bf16(af[rt], bfr[ct], acc2[rt][ct], 0, 0, 0);
  }

  float b2v[4];
#pragma unroll
  for (int ct = 0; ct < 4; ct++) b2v[ct] = b2[cb + ct * 16 + llo];
#pragma unroll
  for (int rt = 0; rt < 4; rt++)
#pragma unroll
    for (int i = 0; i < 4; i++) {
      int r = rt * 16 + lhi * 4 + i;
      if (row0 + r >= A) continue;
#pragma unroll
      for (int ct = 0; ct < 4; ct++) {
        int col = cb + ct * 16 + llo;
        int node = avs[2 * r + (col >> 7)];
        size_t fi = (size_t)node * 128 + (col & 127);
        float y = acc2[rt][ct][i] + b2v[ct] + h[fi];  // residual from global fp32
        atomicAdd(&seg[fi], exp12(y));
      }
    }
}

// arity-1 relation (K=128, D=128)
__global__ __launch_bounds__(256, 2) void k_rel1(
    const float* __restrict__ h, const int* __restrict__ av,
    const __bf16* __restrict__ wt1, const float* __restrict__ b1,
    const __bf16* __restrict__ wt2, const float* __restrict__ b2,
    double* __restrict__ seg, int A) {
  __shared__ __align__(16) __bf16 xs[64][136];
  __shared__ int avs[64];
  const int tid = threadIdx.x;
  const int lane = tid & 63;
  const int w = tid >> 6;
  const int row0 = blockIdx.x * 64;

  if (tid < 64) {
    int a = row0 + tid;
    avs[tid] = (a < A) ? av[a] : 0;
  }
  for (int i = 0; i < 8; ++i) {
    int s = tid + i * 256;      // [0,2048)
    int r = s >> 5, o = s & 31; // 32 chunks x 4 floats = 128
    int a = row0 + r;
    float4 f = {0.f, 0.f, 0.f, 0.f};
    if (a < A) {
      int node = av[a];
      f = *(const float4*)(h + (size_t)node * 128 + o * 4);
    }
    bf16x4 p = {(__bf16)f.x, (__bf16)f.y, (__bf16)f.z, (__bf16)f.w};
    *(bf16x4*)&xs[r][o * 4] = p;
  }
  __syncthreads();

  const int lhi = lane >> 4, llo = lane & 15;
  const int cb = w * 32;

  f32x4 acc1[4][2];
#pragma unroll
  for (int rt = 0; rt < 4; rt++)
#pragma unroll
    for (int ct = 0; ct < 2; ct++) acc1[rt][ct] = (f32x4){0.f, 0.f, 0.f, 0.f};

#pragma unroll
  for (int kk = 0; kk < 4; ++kk) {
    int k = kk * 32 + lhi * 8;
    bf16x8 af[4], bfr[2];
#pragma unroll
    for (int rt = 0; rt < 4; rt++) af[rt] = *(const bf16x8*)&xs[rt * 16 + llo][k];
#pragma unroll
    for (int ct = 0; ct < 2; ct++)
      bfr[ct] = *(const bf16x8*)(wt1 + (size_t)(cb + ct * 16 + llo) * 128 + k);
#pragma unroll
    for (int rt = 0; rt < 4; rt++)
#pragma unroll
      for (int ct = 0; ct < 2; ct++)
        acc1[rt][ct] = __builtin_amdgcn_mfma_f32_16x16x32_bf16(af[rt], bfr[ct], acc1[rt][ct], 0, 0, 0);
  }
  __syncthreads();

  float b1v[2];
#pragma unroll
  for (int ct = 0; ct < 2; ct++) b1v[ct] = b1[cb + ct * 16 + llo];
#pragma unroll
  for (int rt = 0; rt < 4; rt++)
#pragma unroll
    for (int ct = 0; ct < 2; ct++)
#pragma unroll
      for (int i = 0; i < 4; i++)
        xs[rt * 16 + lhi * 4 + i][cb + ct * 16 + llo] = (__bf16)mishf(acc1[rt][ct][i] + b1v[ct]);
  __syncthreads();

  f32x4 acc2[4][2];
#pragma unroll
  for (int rt = 0; rt < 4; rt++)
#pragma unroll
    for (int ct = 0; ct < 2; ct++) acc2[rt][ct] = (f32x4){0.f, 0.f, 0.f, 0.f};

#pragma unroll
  for (int kk = 0; kk < 4; ++kk) {
    int k = kk * 32 + lhi * 8;
    bf16x8 af[4], bfr[2];
#pragma unroll
    for (int rt = 0; rt < 4; rt++) af[rt] = *(const bf16x8*)&xs[rt * 16 + llo][k];
#pragma unroll
    for (int ct = 0; ct < 2; ct++)
      bfr[ct] = *(const bf16x8*)(wt2 + (size_t)(cb + ct * 16 + llo) * 128 + k);
#pragma unroll
    for (int rt = 0; rt < 4; rt++)
#pragma unroll
      for (int ct = 0; ct < 2; ct++)
        acc2[rt][ct] = __builtin_amdgcn_mfma_f32_16x16x32_bf16(af[rt], bfr[ct], acc2[rt][ct], 0, 0, 0);
  }

  float b2v[2];
#pragma unroll
  for (int ct = 0; ct < 2; ct++) b2v[ct] = b2[cb + ct * 16 + llo];
#pragma unroll
  for (int rt = 0; rt < 4; rt++)
#pragma unroll
    for (int i = 0; i < 4; i++) {
      int r = rt * 16 + lhi * 4 + i;
      if (row0 + r >= A) continue;
      int node = avs[r];
#pragma unroll
      for (int ct = 0; ct < 2; ct++) {
        int col = cb + ct * 16 + llo;
        size_t fi = (size_t)node * 128 + col;
        float y = acc2[rt][ct][i] + b2v[ct] + h[fi];
        atomicAdd(&seg[fi], exp12(y));
      }
    }
}

// update: xu=[max_msg(seg), h] (K=256) -> mish MLP -> hout = hin + upd (fp32)
__global__ __launch_bounds__(256, 2) void k_update(
    const float* __restrict__ hin, const double* __restrict__ seg,
    const __bf16* __restrict__ wt1, const float* __restrict__ b1,
    const __bf16* __restrict__ wt2, const float* __restrict__ b2,
    float* __restrict__ hout) {
  __shared__ __align__(16) __bf16 xs[64][264];
  const int tid = threadIdx.x;
  const int lane = tid & 63;
  const int w = tid >> 6;
  const int node0 = blockIdx.x * 64;

  for (int i = 0; i < 32; ++i) {
    int e = tid + i * 256;       // [0,8192)
    int r = e >> 7, f = e & 127;
    int n = node0 + r;
    float v = 0.f;
    if (n < NNODES) v = logS12(seg[(size_t)n * 128 + f]);
    xs[r][f] = (__bf16)v;
  }
  for (int i = 0; i < 8; ++i) {
    int s = tid + i * 256;       // [0,2048)
    int r = s >> 5, o = s & 31;
    int n = node0 + r;
    float4 f = {0.f, 0.f, 0.f, 0.f};
    if (n < NNODES) f = *(const float4*)(hin + (size_t)n * 128 + o * 4);
    bf16x4 p = {(__bf16)f.x, (__bf16)f.y, (__bf16)f.z, (__bf16)f.w};
    *(bf16x4*)&xs[r][128 + o * 4] = p;
  }
  __syncthreads();

  const int lhi = lane >> 4, llo = lane & 15;
  const int cb = w * 64;

  f32x4 acc1[4][4];
#pragma unroll
  for (int rt = 0; rt < 4; rt++)
#pragma unroll
    for (int ct = 0; ct < 4; ct++) acc1[rt][ct] = (f32x4){0.f, 0.f, 0.f, 0.f};

#pragma unroll
  for (int kk = 0; kk < 8; ++kk) {
    int k = kk * 32 + lhi * 8;
    bf16x8 af[4], bfr[4];
#pragma unroll
    for (int rt = 0; rt < 4; rt++) af[rt] = *(const bf16x8*)&xs[rt * 16 + llo][k];
#pragma unroll
    for (int ct = 0; ct < 4; ct++)
      bfr[ct] = *(const bf16x8*)(wt1 + (size_t)(cb + ct * 16 + llo) * 256 + k);
#pragma unroll
    for (int rt = 0; rt < 4; rt++)
#pragma unroll
      for (int ct = 0; ct < 4; ct++)
        acc1[rt][ct] = __builtin_amdgcn_mfma_f32_16x16x32_bf16(af[rt], bfr[ct], acc1[rt][ct], 0, 0, 0);
  }
  __syncthreads();

  float b1v[4];
#pragma unroll
  for (int ct = 0; ct < 4; ct++) b1v[ct] = b1[cb + ct * 16 + llo];
#pragma unroll
  for (int rt = 0; rt < 4; rt++)
#pragma unroll
    for (int ct = 0; ct < 4; ct++)
#pragma unroll
      for (int i = 0; i < 4; i++)
        xs[rt * 16 + lhi * 4 + i][cb + ct * 16 + llo] = (__bf16)mishf(acc1[rt][ct][i] + b1v[ct]);
  __syncthreads();

  const int cb2 = w * 32;
  f32x4 acc2[4][2];
#pragma unroll
  for (int rt = 0; rt < 4; rt++)
#pragma unroll
    for (int ct = 0; ct < 2; ct++) acc2[rt][ct] = (f32x4){0.f, 0.f, 0.f, 0.f};

#pragma unroll
  for (int kk = 0; kk < 8; ++kk) {
    int k = kk * 32 + lhi * 8;
    bf16x8 af[4], bfr[2];
#pragma unroll
    for (int rt = 0; rt < 4; rt++) af[rt] = *(const bf16x8*)&xs[rt * 16 + llo][k];
#pragma unroll
    for (int ct = 0; ct < 2; ct++)
      bfr[ct] = *(const bf16x8*)(wt2 + (size_t)(cb2 + ct * 16 + llo) * 256 + k);
#pragma unroll
    for (int rt = 0; rt < 4; rt++)
#pragma unroll
      for (int ct = 0; ct < 2; ct++)
        acc2[rt][ct] = __builtin_amdgcn_mfma_f32_16x16x32_bf16(af[rt], bfr[ct], acc2[rt][ct], 0, 0, 0);
  }

  float b2v[2];
#pragma unroll
  for (int ct = 0; ct < 2; ct++) b2v[ct] = b2[cb2 + ct * 16 + llo];
#pragma unroll
  for (int rt = 0; rt < 4; rt++)
#pragma unroll
    for (int i = 0; i < 4; i++) {
      int r = rt * 16 + lhi * 4 + i;
      int n = node0 + r;
      if (n >= NNODES) continue;
#pragma unroll
      for (int ct = 0; ct < 2; ct++) {
        int col = cb2 + ct * 16 + llo;
        size_t idx = (size_t)n * 128 + col;
        hout[idx] = hin[idx] + acc2[rt][ct][i] + b2v[ct];
      }
    }
}

extern "C" void kernel_launch(void* const* d_in, const int* in_sizes, int n_in,
                              void* d_out, int out_size, void* d_ws, size_t ws_size,
                              hipStream_t stream) {
  const float* h0 = (const float*)d_in[0];
  const int* at = (const int*)d_in[1];
  const float* w_in_at = (const float*)d_in[2];
  const float* b_in_at = (const float*)d_in[3];
  const float* w_out_at = (const float*)d_in[4];
  const float* b_out_at = (const float*)d_in[5];
  const int* cl = (const int*)d_in[6];
  const float* w_in_cl = (const float*)d_in[7];
  const float* b_in_cl = (const float*)d_in[8];
  const float* w_out_cl = (const float*)d_in[9];
  const float* b_out_cl = (const float*)d_in[10];
  const int* on = (const int*)d_in[11];
  const float* w_in_on = (const float*)d_in[12];
  const float* b_in_on = (const float*)d_in[13];
  const float* w_out_on = (const float*)d_in[14];
  const float* b_out_on = (const float*)d_in[15];
  const float* w_u_in = (const float*)d_in[16];
  const float* b_u_in = (const float*)d_in[17];
  const float* w_u_out = (const float*)d_in[18];
  const float* b_u_out = (const float*)d_in[19];

  const size_t SEG_BYTES = (size_t)NNODES * 128 * 8;  // 102,400,000
  const size_t WT_BYTES = 786432;
  const size_t REQUIRED = SEG_BYTES + WT_BYTES;       // ~103.2 MB

  if (ws_size < REQUIRED) {  // diagnostic sentinel: absmax ~1e6 => workspace too small
    k_sentinel<<<(out_size + 255) / 256, 256, 0, stream>>>((float*)d_out, out_size);
    return;
  }

  char* ws = (char*)d_ws;
  double* seg = (double*)ws;
  __bf16* wt = (__bf16*)(ws + SEG_BYTES);
  __bf16* wt_in_at = wt;
  __bf16* wt_out_at = wt + 65536;
  __bf16* wt_in_on = wt + 131072;
  __bf16* wt_out_on = wt + 196608;
  __bf16* wt_u_in = wt + 262144;
  __bf16* wt_u_out = wt + 327680;
  __bf16* wt_in_cl = wt + 360448;
  __bf16* wt_out_cl = wt + 376832;

  float* hout = (float*)d_out;

  TransDesc td;
  const float* srcs[8] = {w_in_at, w_out_at, w_in_on, w_out_on, w_u_in, w_u_out, w_in_cl, w_out_cl};
  __bf16* dsts[8] = {wt_in_at, wt_out_at, wt_in_on, wt_out_on, wt_u_in, wt_u_out, wt_in_cl, wt_out_cl};
  int Rs[8] = {256, 256, 256, 256, 256, 256, 128, 128};
  int Cs[8] = {256, 256, 256, 256, 256, 128, 128, 128};
  int ts = 0;
  for (int m = 0; m < 8; ++m) {
    td.src[m] = srcs[m];
    td.dst[m] = dsts[m];
    td.R[m] = Rs[m];
    td.C[m] = Cs[m];
    td.tstart[m] = ts;
    ts += (Rs[m] / 32) * (Cs[m] / 32);
  }
  td.tstart[8] = ts;  // 384
  k_transpose_all<<<384, 256, 0, stream>>>(td);

  const int grid_rel = (150000 + 63) / 64;  // 2344
  const int grid_upd = (NNODES + 63) / 64;  // 1563

  for (int l = 0; l < 4; ++l) {
    const float* hs = (l == 0) ? h0 : hout;
    hipMemsetAsync(seg, 0, SEG_BYTES, stream);
    k_rel2<<<grid_rel, 256, 0, stream>>>(hs, at, wt_in_at, b_in_at, wt_out_at, b_out_at, seg, 150000);
    k_rel1<<<grid_rel, 256, 0, stream>>>(hs, cl, wt_in_cl, b_in_cl, wt_out_cl, b_out_cl, seg, 150000);
    k_rel2<<<grid_rel, 256, 0, stream>>>(hs, on, wt_in_on, b_in_on, wt_out_on, b_out_on, seg, 150000);
    k_update<<<grid_upd, 256, 0, stream>>>(hs, seg, wt_u_in, b_u_in, wt_u_out, b_u_out, hout);
  }
}

// Round 3
// 2190.704 us; speedup vs baseline: 1.6417x; 1.6417x over previous
//
#include <hip/hip_runtime.h>
#include <hip/hip_bf16.h>
#include <math.h>

#define NNODES 100000
#define EDIM 128
#define TSLOTS 750000
#define NB 391  // ceil(NNODES/256)

typedef __bf16 bf16x8 __attribute__((ext_vector_type(8)));
typedef __bf16 bf16x4 __attribute__((ext_vector_type(4)));
typedef float f32x4 __attribute__((ext_vector_type(4)));

// mish(x) = x*tanh(softplus(x)) = x*(u^2+2u)/(u^2+2u+2), u=e^x
__device__ __forceinline__ float mishf(float x) {
  float u = __expf(fminf(x, 15.f));
  float num = u * (u + 2.f);
  return x * num * __builtin_amdgcn_rcpf(num + 2.f);
}

// ---- old atomic-path helpers (fallback) ----
__device__ __forceinline__ double exp12(float y) {
  float t = y * 17.312340490667562f;
  t = fminf(fmaxf(t, -20000.f), 20000.f);
  float ti = floorf(t);
  float m = exp2f(t - ti);
  int ei = (int)ti;
  ei = ei < -1000 ? -1000 : (ei > 1000 ? 1000 : ei);
  double sc = __longlong_as_double(((long long)(1023 + ei)) << 52);
  return (double)m * sc;
}
__device__ __forceinline__ float logS12(double S) {
  if (!(S > 0.0)) return -3.0701134f;
  long long b = __double_as_longlong(S);
  int e2 = (int)((b >> 52) & 0x7FF) - 1023;
  float mf = __uint_as_float(0x3F800000u | (unsigned)((b >> 29) & 0x7FFFFF));
  return ((float)e2 + log2f(mf)) * 0.05776226504666211f;
}

__global__ void k_sentinel(float* out, int n) {
  int i = blockIdx.x * 256 + threadIdx.x;
  if (i < n) out[i] = 1.0e6f;
}

struct TransDesc {
  const float* src[8];
  __bf16* dst[8];
  int R[8];
  int C[8];
  int tstart[9];
};

__global__ void k_transpose_all(TransDesc td) {
  __shared__ float tile[32][33];
  int b = blockIdx.x;
  int m = 0;
  while (m < 7 && b >= td.tstart[m + 1]) m++;
  int t = b - td.tstart[m];
  int R = td.R[m], C = td.C[m];
  int tcols = C >> 5;
  int by = t / tcols, bx = t - by * tcols;
  int tx = threadIdx.x & 31, ty = threadIdx.x >> 5;
  const float* src = td.src[m];
  __bf16* dst = td.dst[m];
  for (int i = 0; i < 32; i += 8)
    tile[ty + i][tx] = src[(size_t)(by * 32 + ty + i) * C + bx * 32 + tx];
  __syncthreads();
  for (int i = 0; i < 32; i += 8)
    dst[(size_t)(bx * 32 + ty + i) * R + by * 32 + tx] = (__bf16)tile[tx][ty + i];
}

// ================= CSR build =================
__device__ __forceinline__ int slot_node(int s, const int* at, const int* cl, const int* on) {
  if (s < 300000) return at[s];
  if (s < 450000) return cl[s - 300000];
  return on[s - 450000];
}

__global__ void k_count(const int* __restrict__ at, const int* __restrict__ cl,
                        const int* __restrict__ on, int* __restrict__ cnt) {
  int s = blockIdx.x * 256 + threadIdx.x;
  if (s >= TSLOTS) return;
  atomicAdd(&cnt[slot_node(s, at, cl, on)], 1);
}

__global__ void k_bsum(const int* __restrict__ cnt, int* __restrict__ bsum) {
  __shared__ int sm[256];
  int n = blockIdx.x * 256 + threadIdx.x;
  sm[threadIdx.x] = (n < NNODES) ? cnt[n] : 0;
  __syncthreads();
  for (int st = 128; st > 0; st >>= 1) {
    if (threadIdx.x < st) sm[threadIdx.x] += sm[threadIdx.x + st];
    __syncthreads();
  }
  if (threadIdx.x == 0) bsum[blockIdx.x] = sm[0];
}

__global__ void k_bscan(const int* __restrict__ bsum, int* __restrict__ bpre,
                        int* __restrict__ off) {
  int acc = 0;
  for (int i = 0; i < NB; ++i) {
    bpre[i] = acc;
    acc += bsum[i];
  }
  off[NNODES] = acc;  // = TSLOTS
}

__global__ void k_off(const int* __restrict__ cnt, const int* __restrict__ bpre,
                      int* __restrict__ off) {
  __shared__ int sm[256];
  int n = blockIdx.x * 256 + threadIdx.x;
  int v = (n < NNODES) ? cnt[n] : 0;
  sm[threadIdx.x] = v;
  __syncthreads();
  for (int st = 1; st < 256; st <<= 1) {
    int t = (threadIdx.x >= st) ? sm[threadIdx.x - st] : 0;
    __syncthreads();
    sm[threadIdx.x] += t;
    __syncthreads();
  }
  if (n < NNODES) off[n] = bpre[blockIdx.x] + sm[threadIdx.x] - v;
}

__global__ void k_fill(const int* __restrict__ at, const int* __restrict__ cl,
                       const int* __restrict__ on, const int* __restrict__ off,
                       int* __restrict__ cnt, int* __restrict__ edges) {
  int s = blockIdx.x * 256 + threadIdx.x;
  if (s >= TSLOTS) return;
  int node = slot_node(s, at, cl, on);
  int pos = atomicAdd(&cnt[node], -1) - 1;  // 0..deg-1 (reverse)
  edges[off[node] + pos] = s;
}

// ================= NEW PATH relation kernels: write fp16 msg rows =================
__global__ __launch_bounds__(256, 2) void k_rel2(
    const float* __restrict__ h, const int* __restrict__ av,
    const __bf16* __restrict__ wt1, const float* __restrict__ b1,
    const __bf16* __restrict__ wt2, const float* __restrict__ b2,
    _Float16* __restrict__ msgrel, int A) {
  __shared__ __align__(16) __bf16 xs[64][264];
  __shared__ int avs[128];
  const int tid = threadIdx.x;
  const int lane = tid & 63;
  const int w = tid >> 6;
  const int row0 = blockIdx.x * 64;

  if (tid < 128) {
    int i2 = row0 * 2 + tid;
    avs[tid] = (i2 < 2 * A) ? av[i2] : 0;
  }
  for (int i = 0; i < 16; ++i) {
    int s = tid + i * 256;
    int r = s >> 6, o = s & 63;
    int a = row0 + r;
    float4 f = {0.f, 0.f, 0.f, 0.f};
    if (a < A) {
      int node = av[2 * a + (o >> 5)];
      f = *(const float4*)(h + (size_t)node * 128 + (o & 31) * 4);
    }
    bf16x4 p = {(__bf16)f.x, (__bf16)f.y, (__bf16)f.z, (__bf16)f.w};
    *(bf16x4*)&xs[r][o * 4] = p;
  }
  __syncthreads();

  const int lhi = lane >> 4, llo = lane & 15;
  const int cb = w * 64;

  f32x4 acc1[4][4];
#pragma unroll
  for (int rt = 0; rt < 4; rt++)
#pragma unroll
    for (int ct = 0; ct < 4; ct++) acc1[rt][ct] = (f32x4){0.f, 0.f, 0.f, 0.f};

#pragma unroll
  for (int kk = 0; kk < 8; ++kk) {
    int k = kk * 32 + lhi * 8;
    bf16x8 af[4], bfr[4];
#pragma unroll
    for (int rt = 0; rt < 4; rt++) af[rt] = *(const bf16x8*)&xs[rt * 16 + llo][k];
#pragma unroll
    for (int ct = 0; ct < 4; ct++)
      bfr[ct] = *(const bf16x8*)(wt1 + (size_t)(cb + ct * 16 + llo) * 256 + k);
#pragma unroll
    for (int rt = 0; rt < 4; rt++)
#pragma unroll
      for (int ct = 0; ct < 4; ct++)
        acc1[rt][ct] = __builtin_amdgcn_mfma_f32_16x16x32_bf16(af[rt], bfr[ct], acc1[rt][ct], 0, 0, 0);
  }
  __syncthreads();

  float b1v[4];
#pragma unroll
  for (int ct = 0; ct < 4; ct++) b1v[ct] = b1[cb + ct * 16 + llo];
#pragma unroll
  for (int rt = 0; rt < 4; rt++)
#pragma unroll
    for (int ct = 0; ct < 4; ct++)
#pragma unroll
      for (int i = 0; i < 4; i++)
        xs[rt * 16 + lhi * 4 + i][cb + ct * 16 + llo] = (__bf16)mishf(acc1[rt][ct][i] + b1v[ct]);
  __syncthreads();

  f32x4 acc2[4][4];
#pragma unroll
  for (int rt = 0; rt < 4; rt++)
#pragma unroll
    for (int ct = 0; ct < 4; ct++) acc2[rt][ct] = (f32x4){0.f, 0.f, 0.f, 0.f};

#pragma unroll
  for (int kk = 0; kk < 8; ++kk) {
    int k = kk * 32 + lhi * 8;
    bf16x8 af[4], bfr[4];
#pragma unroll
    for (int rt = 0; rt < 4; rt++) af[rt] = *(const bf16x8*)&xs[rt * 16 + llo][k];
#pragma unroll
    for (int ct = 0; ct < 4; ct++)
      bfr[ct] = *(const bf16x8*)(wt2 + (size_t)(cb + ct * 16 + llo) * 256 + k);
#pragma unroll
    for (int rt = 0; rt < 4; rt++)
#pragma unroll
      for (int ct = 0; ct < 4; ct++)
        acc2[rt][ct] = __builtin_amdgcn_mfma_f32_16x16x32_bf16(af[rt], bfr[ct], acc2[rt][ct], 0, 0, 0);
  }
  __syncthreads();  // all xs reads done

  // stage z = acc2 + b2 to LDS fp16
  float b2v[4];
#pragma unroll
  for (int ct = 0; ct < 4; ct++) b2v[ct] = b2[cb + ct * 16 + llo];
  ushort* zs = (ushort*)&xs[0][0];  // row stride 264 ushorts
#pragma unroll
  for (int rt = 0; rt < 4; rt++)
#pragma unroll
    for (int ct = 0; ct < 4; ct++)
#pragma unroll
      for (int i = 0; i < 4; i++) {
        int r = rt * 16 + lhi * 4 + i;
        int col = cb + ct * 16 + llo;
        union { ushort u; _Float16 f; } cv;
        cv.f = (_Float16)(acc2[rt][ct][i] + b2v[ct]);
        zs[r * 264 + col] = cv.u;
      }
  __syncthreads();

  // write-out: 128 slot-rows x 128 fp16; residual h read coalesced
  for (int i = 0; i < 8; ++i) {
    int s = tid + i * 256;  // 0..2047
    int sr = s >> 4;        // slot-row 0..127
    int c = s & 15;         // 8-feat chunk
    int a = row0 + (sr >> 1);
    if (a < A) {
      int node = avs[sr];
      int rr = sr >> 1, c0 = (sr & 1) * 128 + c * 8;
      const float* hp = h + (size_t)node * 128 + c * 8;
      float4 h0 = *(const float4*)hp;
      float4 h1 = *(const float4*)(hp + 4);
      union { uint4 u; _Float16 f[8]; } zu, yu;
      zu.u = *(const uint4*)&zs[rr * 264 + c0];
      yu.f[0] = (_Float16)((float)zu.f[0] + h0.x);
      yu.f[1] = (_Float16)((float)zu.f[1] + h0.y);
      yu.f[2] = (_Float16)((float)zu.f[2] + h0.z);
      yu.f[3] = (_Float16)((float)zu.f[3] + h0.w);
      yu.f[4] = (_Float16)((float)zu.f[4] + h1.x);
      yu.f[5] = (_Float16)((float)zu.f[5] + h1.y);
      yu.f[6] = (_Float16)((float)zu.f[6] + h1.z);
      yu.f[7] = (_Float16)((float)zu.f[7] + h1.w);
      *(uint4*)(msgrel + ((size_t)(row0 * 2 + sr)) * 128 + c * 8) = yu.u;
    }
  }
}

__global__ __launch_bounds__(256, 2) void k_rel1(
    const float* __restrict__ h, const int* __restrict__ av,
    const __bf16* __restrict__ wt1, const float* __restrict__ b1,
    const __bf16* __restrict__ wt2, const float* __restrict__ b2,
    _Float16* __restrict__ msgrel, int A) {
  __shared__ __align__(16) __bf16 xs[64][136];
  __shared__ int avs[64];
  const int tid = threadIdx.x;
  const int lane = tid & 63;
  const int w = tid >> 6;
  const int row0 = blockIdx.x * 64;

  if (tid < 64) {
    int a = row0 + tid;
    avs[tid] = (a < A) ? av[a] : 0;
  }
  for (int i = 0; i < 8; ++i) {
    int s = tid + i * 256;
    int r = s >> 5, o = s & 31;
    int a = row0 + r;
    float4 f = {0.f, 0.f, 0.f, 0.f};
    if (a < A) {
      int node = av[a];
      f = *(const float4*)(h + (size_t)node * 128 + o * 4);
    }
    bf16x4 p = {(__bf16)f.x, (__bf16)f.y, (__bf16)f.z, (__bf16)f.w};
    *(bf16x4*)&xs[r][o * 4] = p;
  }
  __syncthreads();

  const int lhi = lane >> 4, llo = lane & 15;
  const int cb = w * 32;

  f32x4 acc1[4][2];
#pragma unroll
  for (int rt = 0; rt < 4; rt++)
#pragma unroll
    for (int ct = 0; ct < 2; ct++) acc1[rt][ct] = (f32x4){0.f, 0.f, 0.f, 0.f};

#pragma unroll
  for (int kk = 0; kk < 4; ++kk) {
    int k = kk * 32 + lhi * 8;
    bf16x8 af[4], bfr[2];
#pragma unroll
    for (int rt = 0; rt < 4; rt++) af[rt] = *(const bf16x8*)&xs[rt * 16 + llo][k];
#pragma unroll
    for (int ct = 0; ct < 2; ct++)
      bfr[ct] = *(const bf16x8*)(wt1 + (size_t)(cb + ct * 16 + llo) * 128 + k);
#pragma unroll
    for (int rt = 0; rt < 4; rt++)
#pragma unroll
      for (int ct = 0; ct < 2; ct++)
        acc1[rt][ct] = __builtin_amdgcn_mfma_f32_16x16x32_bf16(af[rt], bfr[ct], acc1[rt][ct], 0, 0, 0);
  }
  __syncthreads();

  float b1v[2];
#pragma unroll
  for (int ct = 0; ct < 2; ct++) b1v[ct] = b1[cb + ct * 16 + llo];
#pragma unroll
  for (int rt = 0; rt < 4; rt++)
#pragma unroll
    for (int ct = 0; ct < 2; ct++)
#pragma unroll
      for (int i = 0; i < 4; i++)
        xs[rt * 16 + lhi * 4 + i][cb + ct * 16 + llo] = (__bf16)mishf(acc1[rt][ct][i] + b1v[ct]);
  __syncthreads();

  f32x4 acc2[4][2];
#pragma unroll
  for (int rt = 0; rt < 4; rt++)
#pragma unroll
    for (int ct = 0; ct < 2; ct++) acc2[rt][ct] = (f32x4){0.f, 0.f, 0.f, 0.f};

#pragma unroll
  for (int kk = 0; kk < 4; ++kk) {
    int k = kk * 32 + lhi * 8;
    bf16x8 af[4], bfr[2];
#pragma unroll
    for (int rt = 0; rt < 4; rt++) af[rt] = *(const bf16x8*)&xs[rt * 16 + llo][k];
#pragma unroll
    for (int ct = 0; ct < 2; ct++)
      bfr[ct] = *(const bf16x8*)(wt2 + (size_t)(cb + ct * 16 + llo) * 128 + k);
#pragma unroll
    for (int rt = 0; rt < 4; rt++)
#pragma unroll
      for (int ct = 0; ct < 2; ct++)
        acc2[rt][ct] = __builtin_amdgcn_mfma_f32_16x16x32_bf16(af[rt], bfr[ct], acc2[rt][ct], 0, 0, 0);
  }
  __syncthreads();

  float b2v[2];
#pragma unroll
  for (int ct = 0; ct < 2; ct++) b2v[ct] = b2[cb + ct * 16 + llo];
  ushort* zs = (ushort*)&xs[0][0];  // row stride 136
#pragma unroll
  for (int rt = 0; rt < 4; rt++)
#pragma unroll
    for (int ct = 0; ct < 2; ct++)
#pragma unroll
      for (int i = 0; i < 4; i++) {
        int r = rt * 16 + lhi * 4 + i;
        int col = cb + ct * 16 + llo;
        union { ushort u; _Float16 f; } cv;
        cv.f = (_Float16)(acc2[rt][ct][i] + b2v[ct]);
        zs[r * 136 + col] = cv.u;
      }
  __syncthreads();

  for (int i = 0; i < 4; ++i) {
    int s = tid + i * 256;  // 0..1023
    int sr = s >> 4;        // 0..63
    int c = s & 15;
    int a = row0 + sr;
    if (a < A) {
      int node = avs[sr];
      const float* hp = h + (size_t)node * 128 + c * 8;
      float4 h0 = *(const float4*)hp;
      float4 h1 = *(const float4*)(hp + 4);
      union { uint4 u; _Float16 f[8]; } zu, yu;
      zu.u = *(const uint4*)&zs[sr * 136 + c * 8];
      yu.f[0] = (_Float16)((float)zu.f[0] + h0.x);
      yu.f[1] = (_Float16)((float)zu.f[1] + h0.y);
      yu.f[2] = (_Float16)((float)zu.f[2] + h0.z);
      yu.f[3] = (_Float16)((float)zu.f[3] + h0.w);
      yu.f[4] = (_Float16)((float)zu.f[4] + h1.x);
      yu.f[5] = (_Float16)((float)zu.f[5] + h1.y);
      yu.f[6] = (_Float16)((float)zu.f[6] + h1.z);
      yu.f[7] = (_Float16)((float)zu.f[7] + h1.w);
      *(uint4*)(msgrel + ((size_t)(row0 + sr)) * 128 + c * 8) = yu.u;
    }
  }
}

// update: per-node online logsumexp over CSR edges -> max_msg; then MLP
__global__ __launch_bounds__(256, 2) void k_update(
    const float* __restrict__ hin, const _Float16* __restrict__ msg,
    const int* __restrict__ off, const int* __restrict__ edges,
    const __bf16* __restrict__ wt1, const float* __restrict__ b1,
    const __bf16* __restrict__ wt2, const float* __restrict__ b2,
    float* __restrict__ hout) {
  __shared__ __align__(16) __bf16 xs[64][264];
  const int tid = threadIdx.x;
  const int lane = tid & 63;
  const int w = tid >> 6;
  const int node0 = blockIdx.x * 64;

  // h staging (cols 128..255)
  for (int i = 0; i < 8; ++i) {
    int s = tid + i * 256;
    int r = s >> 5, o = s & 31;
    int n = node0 + r;
    float4 f = {0.f, 0.f, 0.f, 0.f};
    if (n < NNODES) f = *(const float4*)(hin + (size_t)n * 128 + o * 4);
    bf16x4 p = {(__bf16)f.x, (__bf16)f.y, (__bf16)f.z, (__bf16)f.w};
    *(bf16x4*)&xs[r][128 + o * 4] = p;
  }

  // aggregation: wave w handles nodes node0 + w*16 + j; lane covers feats {2l, 2l+1}
  for (int j = 0; j < 16; ++j) {
    int n = node0 + w * 16 + j;
    float m0 = -1e30f, s0 = 0.f, m1 = -1e30f, s1 = 0.f;
    if (n < NNODES) {
      int beg = off[n], end = off[n + 1];
      int e = beg;
      for (; e + 2 <= end; e += 2) {
        int sl0 = edges[e], sl1 = edges[e + 1];
        uint p0 = *(const uint*)(msg + (size_t)sl0 * 128 + lane * 2);
        uint p1 = *(const uint*)(msg + (size_t)sl1 * 128 + lane * 2);
        union { uint u; _Float16 f[2]; } q;
        q.u = p0;
        {
          float y0 = (float)q.f[0] * 12.f, y1 = (float)q.f[1] * 12.f;
          float nm0 = fmaxf(m0, y0), nm1 = fmaxf(m1, y1);
          s0 = s0 * __expf(m0 - nm0) + __expf(y0 - nm0);
          s1 = s1 * __expf(m1 - nm1) + __expf(y1 - nm1);
          m0 = nm0; m1 = nm1;
        }
        q.u = p1;
        {
          float y0 = (float)q.f[0] * 12.f, y1 = (float)q.f[1] * 12.f;
          float nm0 = fmaxf(m0, y0), nm1 = fmaxf(m1, y1);
          s0 = s0 * __expf(m0 - nm0) + __expf(y0 - nm0);
          s1 = s1 * __expf(m1 - nm1) + __expf(y1 - nm1);
          m0 = nm0; m1 = nm1;
        }
      }
      if (e < end) {
        int sl0 = edges[e];
        union { uint u; _Float16 f[2]; } q;
        q.u = *(const uint*)(msg + (size_t)sl0 * 128 + lane * 2);
        float y0 = (float)q.f[0] * 12.f, y1 = (float)q.f[1] * 12.f;
        float nm0 = fmaxf(m0, y0), nm1 = fmaxf(m1, y1);
        s0 = s0 * __expf(m0 - nm0) + __expf(y0 - nm0);
        s1 = s1 * __expf(m1 - nm1) + __expf(y1 - nm1);
        m0 = nm0; m1 = nm1;
      }
    }
    float v0 = (s0 > 0.f) ? (m0 + __logf(s0)) * 0.08333333333f : -3.0701134f;
    float v1 = (s1 > 0.f) ? (m1 + __logf(s1)) * 0.08333333333f : -3.0701134f;
    union { uint u; __bf16 b[2]; } pk;
    pk.b[0] = (__bf16)v0;
    pk.b[1] = (__bf16)v1;
    *(uint*)&xs[w * 16 + j][2 * lane] = pk.u;
  }
  __syncthreads();

  const int lhi = lane >> 4, llo = lane & 15;
  const int cb = w * 64;

  f32x4 acc1[4][4];
#pragma unroll
  for (int rt = 0; rt < 4; rt++)
#pragma unroll
    for (int ct = 0; ct < 4; ct++) acc1[rt][ct] = (f32x4){0.f, 0.f, 0.f, 0.f};

#pragma unroll
  for (int kk = 0; kk < 8; ++kk) {
    int k = kk * 32 + lhi * 8;
    bf16x8 af[4], bfr[4];
#pragma unroll
    for (int rt = 0; rt < 4; rt++) af[rt] = *(const bf16x8*)&xs[rt * 16 + llo][k];
#pragma unroll
    for (int ct = 0; ct < 4; ct++)
      bfr[ct] = *(const bf16x8*)(wt1 + (size_t)(cb + ct * 16 + llo) * 256 + k);
#pragma unroll
    for (int rt = 0; rt < 4; rt++)
#pragma unroll
      for (int ct = 0; ct < 4; ct++)
        acc1[rt][ct] = __builtin_amdgcn_mfma_f32_16x16x32_bf16(af[rt], bfr[ct], acc1[rt][ct], 0, 0, 0);
  }
  __syncthreads();

  float b1v[4];
#pragma unroll
  for (int ct = 0; ct < 4; ct++) b1v[ct] = b1[cb + ct * 16 + llo];
#pragma unroll
  for (int rt = 0; rt < 4; rt++)
#pragma unroll
    for (int ct = 0; ct < 4; ct++)
#pragma unroll
      for (int i = 0; i < 4; i++)
        xs[rt * 16 + lhi * 4 + i][cb + ct * 16 + llo] = (__bf16)mishf(acc1[rt][ct][i] + b1v[ct]);
  __syncthreads();

  const int cb2 = w * 32;
  f32x4 acc2[4][2];
#pragma unroll
  for (int rt = 0; rt < 4; rt++)
#pragma unroll
    for (int ct = 0; ct < 2; ct++) acc2[rt][ct] = (f32x4){0.f, 0.f, 0.f, 0.f};

#pragma unroll
  for (int kk = 0; kk < 8; ++kk) {
    int k = kk * 32 + lhi * 8;
    bf16x8 af[4], bfr[2];
#pragma unroll
    for (int rt = 0; rt < 4; rt++) af[rt] = *(const bf16x8*)&xs[rt * 16 + llo][k];
#pragma unroll
    for (int ct = 0; ct < 2; ct++)
      bfr[ct] = *(const bf16x8*)(wt2 + (size_t)(cb2 + ct * 16 + llo) * 256 + k);
#pragma unroll
    for (int rt = 0; rt < 4; rt++)
#pragma unroll
      for (int ct = 0; ct < 2; ct++)
        acc2[rt][ct] = __builtin_amdgcn_mfma_f32_16x16x32_bf16(af[rt], bfr[ct], acc2[rt][ct], 0, 0, 0);
  }

  float b2v[2];
#pragma unroll
  for (int ct = 0; ct < 2; ct++) b2v[ct] = b2[cb2 + ct * 16 + llo];
#pragma unroll
  for (int rt = 0; rt < 4; rt++)
#pragma unroll
    for (int i = 0; i < 4; i++) {
      int r = rt * 16 + lhi * 4 + i;
      int n = node0 + r;
      if (n >= NNODES) continue;
#pragma unroll
      for (int ct = 0; ct < 2; ct++) {
        int col = cb2 + ct * 16 + llo;
        size_t idx = (size_t)n * 128 + col;
        hout[idx] = hin[idx] + acc2[rt][ct][i] + b2v[ct];
      }
    }
}

// ================= FALLBACK (round-2 atomic path) =================
__global__ __launch_bounds__(256, 2) void k_rel2_a(
    const float* __restrict__ h, const int* __restrict__ av,
    const __bf16* __restrict__ wt1, const float* __restrict__ b1,
    const __bf16* __restrict__ wt2, const float* __restrict__ b2,
    double* __restrict__ seg, int A) {
  __shared__ __align__(16) __bf16 xs[64][264];
  __shared__ int avs[128];
  const int tid = threadIdx.x;
  const int lane = tid & 63;
  const int w = tid >> 6;
  const int row0 = blockIdx.x * 64;

  if (tid < 128) {
    int i2 = row0 * 2 + tid;
    avs[tid] = (i2 < 2 * A) ? av[i2] : 0;
  }
  for (int i = 0; i < 16; ++i) {
    int s = tid + i * 256;
    int r = s >> 6, o = s & 63;
    int a = row0 + r;
    float4 f = {0.f, 0.f, 0.f, 0.f};
    if (a < A) {
      int node = av[2 * a + (o >> 5)];
      f = *(const float4*)(h + (size_t)node * 128 + (o & 31) * 4);
    }
    bf16x4 p = {(__bf16)f.x, (__bf16)f.y, (__bf16)f.z, (__bf16)f.w};
    *(bf16x4*)&xs[r][o * 4] = p;
  }
  __syncthreads();

  const int lhi = lane >> 4, llo = lane & 15;
  const int cb = w * 64;

  f32x4 acc1[4][4];
#pragma unroll
  for (int rt = 0; rt < 4; rt++)
#pragma unroll
    for (int ct = 0; ct < 4; ct++) acc1[rt][ct] = (f32x4){0.f, 0.f, 0.f, 0.f};
#pragma unroll
  for (int kk = 0; kk < 8; ++kk) {
    int k = kk * 32 + lhi * 8;
    bf16x8 af[4], bfr[4];
#pragma unroll
    for (int rt = 0; rt < 4; rt++) af[rt] = *(const bf16x8*)&xs[rt * 16 + llo][k];
#pragma unroll
    for (int ct = 0; ct < 4; ct++)
      bfr[ct] = *(const bf16x8*)(wt1 + (size_t)(cb + ct * 16 + llo) * 256 + k);
#pragma unroll
    for (int rt = 0; rt < 4; rt++)
#pragma unroll
      for (int ct = 0; ct < 4; ct++)
        acc1[rt][ct] = __builtin_amdgcn_mfma_f32_16x16x32_bf16(af[rt], bfr[ct], acc1[rt][ct], 0, 0, 0);
  }
  __syncthreads();
  float b1v[4];
#pragma unroll
  for (int ct = 0; ct < 4; ct++) b1v[ct] = b1[cb + ct * 16 + llo];
#pragma unroll
  for (int rt = 0; rt < 4; rt++)
#pragma unroll
    for (int ct = 0; ct < 4; ct++)
#pragma unroll
      for (int i = 0; i < 4; i++)
        xs[rt * 16 + lhi * 4 + i][cb + ct * 16 + llo] = (__bf16)mishf(acc1[rt][ct][i] + b1v[ct]);
  __syncthreads();
  f32x4 acc2[4][4];
#pragma unroll
  for (int rt = 0; rt < 4; rt++)
#pragma unroll
    for (int ct = 0; ct < 4; ct++) acc2[rt][ct] = (f32x4){0.f, 0.f, 0.f, 0.f};
#pragma unroll
  for (int kk = 0; kk < 8; ++kk) {
    int k = kk * 32 + lhi * 8;
    bf16x8 af[4], bfr[4];
#pragma unroll
    for (int rt = 0; rt < 4; rt++) af[rt] = *(const bf16x8*)&xs[rt * 16 + llo][k];
#pragma unroll
    for (int ct = 0; ct < 4; ct++)
      bfr[ct] = *(const bf16x8*)(wt2 + (size_t)(cb + ct * 16 + llo) * 256 + k);
#pragma unroll
    for (int rt = 0; rt < 4; rt++)
#pragma unroll
      for (int ct = 0; ct < 4; ct++)
        acc2[rt][ct] = __builtin_amdgcn_mfma_f32_16x16x32_bf16(af[rt], bfr[ct], acc2[rt][ct], 0, 0, 0);
  }
  float b2v[4];
#pragma unroll
  for (int ct = 0; ct < 4; ct++) b2v[ct] = b2[cb + ct * 16 + llo];
#pragma unroll
  for (int rt = 0; rt < 4; rt++)
#pragma unroll
    for (int i = 0; i < 4; i++) {
      int r = rt * 16 + lhi * 4 + i;
      if (row0 + r >= A) continue;
#pragma unroll
      for (int ct = 0; ct < 4; ct++) {
        int col = cb + ct * 16 + llo;
        int node = avs[2 * r + (col >> 7)];
        size_t fi = (size_t)node * 128 + (col & 127);
        float y = acc2[rt][ct][i] + b2v[ct] + h[fi];
        atomicAdd(&seg[fi], exp12(y));
      }
    }
}

__global__ __launch_bounds__(256, 2) void k_rel1_a(
    const float* __restrict__ h, const int* __restrict__ av,
    const __bf16* __restrict__ wt1, const float* __restrict__ b1,
    const __bf16* __restrict__ wt2, const float* __restrict__ b2,
    double* __restrict__ seg, int A) {
  __shared__ __align__(16) __bf16 xs[64][136];
  __shared__ int avs[64];
  const int tid = threadIdx.x;
  const int lane = tid & 63;
  const int w = tid >> 6;
  const int row0 = blockIdx.x * 64;

  if (tid < 64) {
    int a = row0 + tid;
    avs[tid] = (a < A) ? av[a] : 0;
  }
  for (int i = 0; i < 8; ++i) {
    int s = tid + i * 256;
    int r = s >> 5, o = s & 31;
    int a = row0 + r;
    float4 f = {0.f, 0.f, 0.f, 0.f};
    if (a < A) {
      int node = av[a];
      f = *(const float4*)(h + (size_t)node * 128 + o * 4);
    }
    bf16x4 p = {(__bf16)f.x, (__bf16)f.y, (__bf16)f.z, (__bf16)f.w};
    *(bf16x4*)&xs[r][o * 4] = p;
  }
  __syncthreads();
  const int lhi = lane >> 4, llo = lane & 15;
  const int cb = w * 32;
  f32x4 acc1[4][2];
#pragma unroll
  for (int rt = 0; rt < 4; rt++)
#pragma unroll
    for (int ct = 0; ct < 2; ct++) acc1[rt][ct] = (f32x4){0.f, 0.f, 0.f, 0.f};
#pragma unroll
  for (int kk = 0; kk < 4; ++kk) {
    int k = kk * 32 + lhi * 8;
    bf16x8 af[4], bfr[2];
#pragma unroll
    for (int rt = 0; rt < 4; rt++) af[rt] = *(const bf16x8*)&xs[rt * 16 + llo][k];
#pragma unroll
    for (int ct = 0; ct < 2; ct++)
      bfr[ct] = *(const bf16x8*)(wt1 + (size_t)(cb + ct * 16 + llo) * 128 + k);
#pragma unroll
    for (int rt = 0; rt < 4; rt++)
#pragma unroll
      for (int ct = 0; ct < 2; ct++)
        acc1[rt][ct] = __builtin_amdgcn_mfma_f32_16x16x32_bf16(af[rt], bfr[ct], acc1[rt][ct], 0, 0, 0);
  }
  __syncthreads();
  float b1v[2];
#pragma unroll
  for (int ct = 0; ct < 2; ct++) b1v[ct] = b1[cb + ct * 16 + llo];
#pragma unroll
  for (int rt = 0; rt < 4; rt++)
#pragma unroll
    for (int ct = 0; ct < 2; ct++)
#pragma unroll
      for (int i = 0; i < 4; i++)
        xs[rt * 16 + lhi * 4 + i][cb + ct * 16 + llo] = (__bf16)mishf(acc1[rt][ct][i] + b1v[ct]);
  __syncthreads();
  f32x4 acc2[4][2];
#pragma unroll
  for (int rt = 0; rt < 4; rt++)
#pragma unroll
    for (int ct = 0; ct < 2; ct++) acc2[rt][ct] = (f32x4){0.f, 0.f, 0.f, 0.f};
#pragma unroll
  for (int kk = 0; kk < 4; ++kk) {
    int k = kk * 32 + lhi * 8;
    bf16x8 af[4], bfr[2];
#pragma unroll
    for (int rt = 0; rt < 4; rt++) af[rt] = *(const bf16x8*)&xs[rt * 16 + llo][k];
#pragma unroll
    for (int ct = 0; ct < 2; ct++)
      bfr[ct] = *(const bf16x8*)(wt2 + (size_t)(cb + ct * 16 + llo) * 128 + k);
#pragma unroll
    for (int rt = 0; rt < 4; rt++)
#pragma unroll
      for (int ct = 0; ct < 2; ct++)
        acc2[rt][ct] = __builtin_amdgcn_mfma_f32_16x16x32_bf16(af[rt], bfr[ct], acc2[rt][ct], 0, 0, 0);
  }
  float b2v[2];
#pragma unroll
  for (int ct = 0; ct < 2; ct++) b2v[ct] = b2[cb + ct * 16 + llo];
#pragma unroll
  for (int rt = 0; rt < 4; rt++)
#pragma unroll
    for (int i = 0; i < 4; i++) {
      int r = rt * 16 + lhi * 4 + i;
      if (row0 + r >= A) continue;
      int node = avs[r];
#pragma unroll
      for (int ct = 0; ct < 2; ct++) {
        int col = cb + ct * 16 + llo;
        size_t fi = (size_t)node * 128 + col;
        float y = acc2[rt][ct][i] + b2v[ct] + h[fi];
        atomicAdd(&seg[fi], exp12(y));
      }
    }
}

__global__ __launch_bounds__(256, 2) void k_update_a(
    const float* __restrict__ hin, const double* __restrict__ seg,
    const __bf16* __restrict__ wt1, const float* __restrict__ b1,
    const __bf16* __restrict__ wt2, const float* __restrict__ b2,
    float* __restrict__ hout) {
  __shared__ __align__(16) __bf16 xs[64][264];
  const int tid = threadIdx.x;
  const int lane = tid & 63;
  const int w = tid >> 6;
  const int node0 = blockIdx.x * 64;

  for (int i = 0; i < 32; ++i) {
    int e = tid + i * 256;
    int r = e >> 7, f = e & 127;
    int n = node0 + r;
    float v = 0.f;
    if (n < NNODES) v = logS12(seg[(size_t)n * 128 + f]);
    xs[r][f] = (__bf16)v;
  }
  for (int i = 0; i < 8; ++i) {
    int s = tid + i * 256;
    int r = s >> 5, o = s & 31;
    int n = node0 + r;
    float4 f = {0.f, 0.f, 0.f, 0.f};
    if (n < NNODES) f = *(const float4*)(hin + (size_t)n * 128 + o * 4);
    bf16x4 p = {(__bf16)f.x, (__bf16)f.y, (__bf16)f.z, (__bf16)f.w};
    *(bf16x4*)&xs[r][128 + o * 4] = p;
  }
  __syncthreads();
  const int lhi = lane >> 4, llo = lane & 15;
  const int cb = w * 64;
  f32x4 acc1[4][4];
#pragma unroll
  for (int rt = 0; rt < 4; rt++)
#pragma unroll
    for (int ct = 0; ct < 4; ct++) acc1[rt][ct] = (f32x4){0.f, 0.f, 0.f, 0.f};
#pragma unroll
  for (int kk = 0; kk < 8; ++kk) {
    int k = kk * 32 + lhi * 8;
    bf16x8 af[4], bfr[4];
#pragma unroll
    for (int rt = 0; rt < 4; rt++) af[rt] = *(const bf16x8*)&xs[rt * 16 + llo][k];
#pragma unroll
    for (int ct = 0; ct < 4; ct++)
      bfr[ct] = *(const bf16x8*)(wt1 + (size_t)(cb + ct * 16 + llo) * 256 + k);
#pragma unroll
    for (int rt = 0; rt < 4; rt++)
#pragma unroll
      for (int ct = 0; ct < 4; ct++)
        acc1[rt][ct] = __builtin_amdgcn_mfma_f32_16x16x32_bf16(af[rt], bfr[ct], acc1[rt][ct], 0, 0, 0);
  }
  __syncthreads();
  float b1v[4];
#pragma unroll
  for (int ct = 0; ct < 4; ct++) b1v[ct] = b1[cb + ct * 16 + llo];
#pragma unroll
  for (int rt = 0; rt < 4; rt++)
#pragma unroll
    for (int ct = 0; ct < 4; ct++)
#pragma unroll
      for (int i = 0; i < 4; i++)
        xs[rt * 16 + lhi * 4 + i][cb + ct * 16 + llo] = (__bf16)mishf(acc1[rt][ct][i] + b1v[ct]);
  __syncthreads();
  const int cb2 = w * 32;
  f32x4 acc2[4][2];
#pragma unroll
  for (int rt = 0; rt < 4; rt++)
#pragma unroll
    for (int ct = 0; ct < 2; ct++) acc2[rt][ct] = (f32x4){0.f, 0.f, 0.f, 0.f};
#pragma unroll
  for (int kk = 0; kk < 8; ++kk) {
    int k = kk * 32 + lhi * 8;
    bf16x8 af[4], bfr[2];
#pragma unroll
    for (int rt = 0; rt < 4; rt++) af[rt] = *(const bf16x8*)&xs[rt * 16 + llo][k];
#pragma unroll
    for (int ct = 0; ct < 2; ct++)
      bfr[ct] = *(const bf16x8*)(wt2 + (size_t)(cb2 + ct * 16 + llo) * 256 + k);
#pragma unroll
    for (int rt = 0; rt < 4; rt++)
#pragma unroll
      for (int ct = 0; ct < 2; ct++)
        acc2[rt][ct] = __builtin_amdgcn_mfma_f32_16x16x32_bf16(af[rt], bfr[ct], acc2[rt][ct], 0, 0, 0);
  }
  float b2v[2];
#pragma unroll
  for (int ct = 0; ct < 2; ct++) b2v[ct] = b2[cb2 + ct * 16 + llo];
#pragma unroll
  for (int rt = 0; rt < 4; rt++)
#pragma unroll
    for (int i = 0; i < 4; i++) {
      int r = rt * 16 + lhi * 4 + i;
      int n = node0 + r;
      if (n >= NNODES) continue;
#pragma unroll
      for (int ct = 0; ct < 2; ct++) {
        int col = cb2 + ct * 16 + llo;
        size_t idx = (size_t)n * 128 + col;
        hout[idx] = hin[idx] + acc2[rt][ct][i] + b2v[ct];
      }
    }
}

extern "C" void kernel_launch(void* const* d_in, const int* in_sizes, int n_in,
                              void* d_out, int out_size, void* d_ws, size_t ws_size,
                              hipStream_t stream) {
  const float* h0 = (const float*)d_in[0];
  const int* at = (const int*)d_in[1];
  const float* w_in_at = (const float*)d_in[2];
  const float* b_in_at = (const float*)d_in[3];
  const float* w_out_at = (const float*)d_in[4];
  const float* b_out_at = (const float*)d_in[5];
  const int* cl = (const int*)d_in[6];
  const float* w_in_cl = (const float*)d_in[7];
  const float* b_in_cl = (const float*)d_in[8];
  const float* w_out_cl = (const float*)d_in[9];
  const float* b_out_cl = (const float*)d_in[10];
  const int* on = (const int*)d_in[11];
  const float* w_in_on = (const float*)d_in[12];
  const float* b_in_on = (const float*)d_in[13];
  const float* w_out_on = (const float*)d_in[14];
  const float* b_out_on = (const float*)d_in[15];
  const float* w_u_in = (const float*)d_in[16];
  const float* b_u_in = (const float*)d_in[17];
  const float* w_u_out = (const float*)d_in[18];
  const float* b_u_out = (const float*)d_in[19];

  float* hout = (float*)d_out;
  char* ws = (char*)d_ws;

  // new-path layout
  const size_t MSG_B = (size_t)TSLOTS * 128 * 2;   // 192,000,000
  const size_t OFF_B = 400016;                     // 100001 ints, padded
  const size_t CNT_B = 400000;
  const size_t BS_B = 1568;
  const size_t REQ2 = MSG_B + OFF_B + CNT_B + BS_B * 2 + 3000000 + 786432;
  // fallback layout
  const size_t SEG_B = (size_t)NNODES * 128 * 8;   // 102,400,000
  const size_t REQ1 = SEG_B + 786432;

  const int grid_rel = (150000 + 63) / 64;  // 2344
  const int grid_upd = (NNODES + 63) / 64;  // 1563
  const int grid_slots = (TSLOTS + 255) / 256;  // 2930

  TransDesc td;
  const float* srcs[8] = {w_in_at, w_out_at, w_in_on, w_out_on, w_u_in, w_u_out, w_in_cl, w_out_cl};
  int Rs[8] = {256, 256, 256, 256, 256, 256, 128, 128};
  int Cs[8] = {256, 256, 256, 256, 256, 128, 128, 128};

  if (ws_size >= REQ2) {
    _Float16* msg = (_Float16*)ws;
    int* off = (int*)(ws + MSG_B);
    int* cnt = (int*)(ws + MSG_B + OFF_B);
    int* bsum = (int*)(ws + MSG_B + OFF_B + CNT_B);
    int* bpre = (int*)(ws + MSG_B + OFF_B + CNT_B + BS_B);
    int* edges = (int*)(ws + MSG_B + OFF_B + CNT_B + 2 * BS_B);
    __bf16* wt = (__bf16*)(ws + MSG_B + OFF_B + CNT_B + 2 * BS_B + 3000000);

    __bf16* wt_in_at = wt;
    __bf16* wt_out_at = wt + 65536;
    __bf16* wt_in_on = wt + 131072;
    __bf16* wt_out_on = wt + 196608;
    __bf16* wt_u_in = wt + 262144;
    __bf16* wt_u_out = wt + 327680;
    __bf16* wt_in_cl = wt + 360448;
    __bf16* wt_out_cl = wt + 376832;
    __bf16* dsts[8] = {wt_in_at, wt_out_at, wt_in_on, wt_out_on, wt_u_in, wt_u_out, wt_in_cl, wt_out_cl};
    int ts = 0;
    for (int m = 0; m < 8; ++m) {
      td.src[m] = srcs[m]; td.dst[m] = dsts[m]; td.R[m] = Rs[m]; td.C[m] = Cs[m];
      td.tstart[m] = ts; ts += (Rs[m] / 32) * (Cs[m] / 32);
    }
    td.tstart[8] = ts;
    k_transpose_all<<<384, 256, 0, stream>>>(td);

    // CSR build (per call; atom arrays are call-constant)
    hipMemsetAsync(cnt, 0, CNT_B, stream);
    k_count<<<grid_slots, 256, 0, stream>>>(at, cl, on, cnt);
    k_bsum<<<NB, 256, 0, stream>>>(cnt, bsum);
    k_bscan<<<1, 1, 0, stream>>>(bsum, bpre, off);
    k_off<<<NB, 256, 0, stream>>>(cnt, bpre, off);
    k_fill<<<grid_slots, 256, 0, stream>>>(at, cl, on, off, cnt, edges);

    _Float16* msg_at = msg;                       // slots [0, 300000)
    _Float16* msg_cl = msg + (size_t)300000 * 128;  // slots [300000, 450000)
    _Float16* msg_on = msg + (size_t)450000 * 128;  // slots [450000, 750000)

    for (int l = 0; l < 4; ++l) {
      const float* hs = (l == 0) ? h0 : hout;
      k_rel2<<<grid_rel, 256, 0, stream>>>(hs, at, wt_in_at, b_in_at, wt_out_at, b_out_at, msg_at, 150000);
      k_rel1<<<grid_rel, 256, 0, stream>>>(hs, cl, wt_in_cl, b_in_cl, wt_out_cl, b_out_cl, msg_cl, 150000);
      k_rel2<<<grid_rel, 256, 0, stream>>>(hs, on, wt_in_on, b_in_on, wt_out_on, b_out_on, msg_on, 150000);
      k_update<<<grid_upd, 256, 0, stream>>>(hs, msg, off, edges, wt_u_in, b_u_in, wt_u_out, b_u_out, hout);
    }
  } else if (ws_size >= REQ1) {
    double* seg = (double*)ws;
    __bf16* wt = (__bf16*)(ws + SEG_B);
    __bf16* wt_in_at = wt;
    __bf16* wt_out_at = wt + 65536;
    __bf16* wt_in_on = wt + 131072;
    __bf16* wt_out_on = wt + 196608;
    __bf16* wt_u_in = wt + 262144;
    __bf16* wt_u_out = wt + 327680;
    __bf16* wt_in_cl = wt + 360448;
    __bf16* wt_out_cl = wt + 376832;
    __bf16* dsts[8] = {wt_in_at, wt_out_at, wt_in_on, wt_out_on, wt_u_in, wt_u_out, wt_in_cl, wt_out_cl};
    int ts = 0;
    for (int m = 0; m < 8; ++m) {
      td.src[m] = srcs[m]; td.dst[m] = dsts[m]; td.R[m] = Rs[m]; td.C[m] = Cs[m];
      td.tstart[m] = ts; ts += (Rs[m] / 32) * (Cs[m] / 32);
    }
    td.tstart[8] = ts;
    k_transpose_all<<<384, 256, 0, stream>>>(td);

    for (int l = 0; l < 4; ++l) {
      const float* hs = (l == 0) ? h0 : hout;
      hipMemsetAsync(seg, 0, SEG_B, stream);
      k_rel2_a<<<grid_rel, 256, 0, stream>>>(hs, at, wt_in_at, b_in_at, wt_out_at, b_out_at, seg, 150000);
      k_rel1_a<<<grid_rel, 256, 0, stream>>>(hs, cl, wt_in_cl, b_in_cl, wt_out_cl, b_out_cl, seg, 150000);
      k_rel2_a<<<grid_rel, 256, 0, stream>>>(hs, on, wt_in_on, b_in_on, wt_out_on, b_out_on, seg, 150000);
      k_update_a<<<grid_upd, 256, 0, stream>>>(hs, seg, wt_u_in, b_u_in, wt_u_out, b_u_out, hout);
    }
  } else {
    k_sentinel<<<(out_size + 255) / 256, 256, 0, stream>>>((float*)d_out, out_size);
  }
}